// Round 4
// baseline (8284.623 us; speedup 1.0000x reference)
//
#include <hip/hip_runtime.h>
#include <hip/hip_bf16.h>
#include <math.h>

// Round 4: one WAVE per batch element, BARRIER-FREE main loop.
//  - Token state [32][64] fp32 in registers (MFMA C-layout); LN via DPP rowsum.
//  - Fragment repacks via per-wave LDS round trips (lgkm only, no barriers).
//  - ciW/coW fragments read directly from L2 (ws, prepacked) - no block cache,
//    no __syncthreads in the t-loop (waves fully decoupled; 2 waves/SIMD
//    grid-limited, so VGPR budget is 256).
//  - All per-layer LN/bias params staged to LDS once (off the VMEM path).
//  - physW2 stored fp32 in ws (kills 64 bf16 unpacks/step).
//
// Fragment layouts (gfx950, verified m89/m91 + rounds 2-3):
//   A[m=lane&15][k=(lane>>4)*8+j], B[k=(lane>>4)*8+j][n=lane&15],
//   C: col=lane&15, row=(lane>>4)*4+reg.

namespace {
constexpr int Tt = 256, NL = 3;

typedef float  f32x4  __attribute__((ext_vector_type(4)));
typedef short  bf16x8 __attribute__((ext_vector_type(8)));
typedef short  bf16x4 __attribute__((ext_vector_type(4)));

#define MFMA16(a, b, c) __builtin_amdgcn_mfma_f32_16x16x32_bf16((a), (b), (c), 0, 0, 0)

__device__ __forceinline__ short f2bf(float x) {
    return __builtin_bit_cast(short, __float2bfloat16(x));
}
// gelu = x * sigmoid(x*(2.3022077 + 0.1029434 x^2))  [tanh-form, exact algebra]
__device__ __forceinline__ float gelu_f(float x) {
    float t = fmaf(x * x, 0.1029434f, 2.3022077f);
    float e = __builtin_amdgcn_exp2f(-x * t);       // neg = free input modifier
    return x * __builtin_amdgcn_rcpf(e + 1.0f);
}
// sum across the 16-lane DPP row (all lanes get the total)
__device__ __forceinline__ float rowsum16(float x) {
    x += __builtin_bit_cast(float, __builtin_amdgcn_update_dpp(0, __builtin_bit_cast(int, x), 0x121, 0xf, 0xf, false));
    x += __builtin_bit_cast(float, __builtin_amdgcn_update_dpp(0, __builtin_bit_cast(int, x), 0x122, 0xf, 0xf, false));
    x += __builtin_bit_cast(float, __builtin_amdgcn_update_dpp(0, __builtin_bit_cast(int, x), 0x124, 0xf, 0xf, false));
    x += __builtin_bit_cast(float, __builtin_amdgcn_update_dpp(0, __builtin_bit_cast(int, x), 0x128, 0xf, 0xf, false));
    return x;
}

// ws layout: shorts tiWF[0,6144) toWF[6144,12288) ciWF[12288,36864) coWF[36864,61440)
//            then fp32 W2F[4096] at byte offset 122880 (= short index 61440)
__global__ void lno_prep(const float* __restrict__ tiW, const float* __restrict__ toW,
                         const float* __restrict__ ciW, const float* __restrict__ coW,
                         const float* __restrict__ physW2, short* __restrict__ wsf) {
    int id = blockIdx.x * 256 + threadIdx.x;  // 0..65535
    if (id < 6144) {            // A1: m=th, k=ld
        int j = id & 7, lane = (id >> 3) & 63, g = id >> 9;
        int il = g >> 2, u = g & 3;
        int m = u * 16 + (lane & 15), k = (lane >> 4) * 8 + j;
        wsf[id] = f2bf(tiW[il * 2048 + k * 64 + m]);
    } else if (id < 12288) {    // A2: m=ld, k=th
        int t = id - 6144;
        int j = t & 7, lane = (t >> 3) & 63, g = t >> 9;
        int il = g >> 2, mt2 = (g >> 1) & 1, ks = g & 1;
        int m = mt2 * 16 + (lane & 15), k = ks * 32 + (lane >> 4) * 8 + j;
        wsf[id] = f2bf(toW[il * 2048 + k * 32 + m]);
    } else if (id < 36864) {    // A3: m=ch, k=w
        int t = id - 12288;
        int j = t & 7, lane = (t >> 3) & 63, g = t >> 9;
        int il = g >> 4, mtc = (g >> 1) & 7, ks = g & 1;
        int m = mtc * 16 + (lane & 15), k = ks * 32 + (lane >> 4) * 8 + j;
        wsf[id] = f2bf(ciW[il * 8192 + k * 128 + m]);
    } else if (id < 61440) {    // B4: k=ch, n=w
        int t = id - 36864;
        int j = t & 7, lane = (t >> 3) & 63, g = t >> 9;
        int il = g >> 4, nt = (g >> 2) & 3, ks = g & 3;
        int n = nt * 16 + (lane & 15), k = ks * 32 + (lane >> 4) * 8 + j;
        wsf[id] = f2bf(coW[il * 8192 + k * 64 + n]);
    } else if (id < 65536) {    // W2F fp32 [w][k]
        int t = id - 61440;
        int w = t >> 6, k = t & 63;
        ((float*)(wsf + 61440))[t] = physW2[k * 64 + w];
    }
}

__global__ __launch_bounds__(256, 2) void lno_scan(
    const float* __restrict__ phys,   const float* __restrict__ latents,
    const float* __restrict__ pos_emb,const float* __restrict__ tokW,
    const float* __restrict__ tokb,   const float* __restrict__ physW1,
    const float* __restrict__ physb1, const float* __restrict__ physb2,
    const float* __restrict__ tn_g,   const float* __restrict__ tn_b,
    const float* __restrict__ tib,    const float* __restrict__ tob,
    const float* __restrict__ cn_g,   const float* __restrict__ cn_b,
    const float* __restrict__ cib,    const float* __restrict__ cob,
    const float* __restrict__ hn_g,   const float* __restrict__ hn_b,
    const float* __restrict__ headW,  const float* __restrict__ headb,
    const short* __restrict__ wsf,    float* __restrict__ out)
{
    __shared__ __align__(16) short bufA[4][2048];   // per-wave: yB (B1) then y2B (B3, swizzled)
    __shared__ __align__(16) short bufB[4][2048];   // per-wave: hB halves (B2) then h2A halves (A4)
    __shared__ __align__(16) float biasL[1632];     // tib[0) tob[192) cib[288) tn_g[672) tn_b[864)
                                                    // cn_g[1056) cn_b[1248) cob[1440)
    __shared__ __align__(16) float pvh[4][128];     // per-wave phys h1 / p exchange

    const short* tiWF = wsf;
    const short* toWF = wsf + 6144;
    const short* ciWF = wsf + 12288;
    const short* coWF = wsf + 36864;
    const float* W2F  = (const float*)(wsf + 61440);

    const int tid = threadIdx.x, lane = tid & 63, wv = tid >> 6;
    const int q = lane >> 4, c = lane & 15;
    const int b = blockIdx.x * 4 + wv;

    short* yb = bufA[wv];
    short* hb = bufB[wv];

    // ---- stage biases + LN params into LDS (once) ----
    for (int i = tid; i < 192; i += 256) {
        biasL[i] = tib[i];
        biasL[672 + i]  = tn_g[i];
        biasL[864 + i]  = tn_b[i];
        biasL[1056 + i] = cn_g[i];
        biasL[1248 + i] = cn_b[i];
        biasL[1440 + i] = cob[i];
    }
    for (int i = tid; i < 96;  i += 256) biasL[192 + i] = tob[i];
    for (int i = tid; i < 384; i += 256) biasL[288 + i] = cib[i];

    // ---- hoisted per-lane constants ----
    float tokw_r[4], tokb_r[4], gh_r[4];
#pragma unroll
    for (int nt = 0; nt < 4; ++nt) {
        tokw_r[nt] = tokW[nt * 16 + c];
        tokb_r[nt] = tokb[nt * 16 + c];
        gh_r[nt]   = hn_g[nt * 16 + c] * headW[nt * 16 + c];
    }
    float bhp = 0.f;
#pragma unroll
    for (int nt = 0; nt < 4; ++nt) bhp = fmaf(hn_b[nt * 16 + c], headW[nt * 16 + c], bhp);
    const float bh = rowsum16(bhp) + headb[0];

    float pe_r[2][4][4];
#pragma unroll
    for (int mt = 0; mt < 2; ++mt)
#pragma unroll
        for (int nt = 0; nt < 4; ++nt)
#pragma unroll
            for (int r = 0; r < 4; ++r)
                pe_r[mt][nt][r] = pos_emb[(mt * 16 + q * 4 + r) * 64 + nt * 16 + c];

    float w1_r[8];
#pragma unroll
    for (int k = 0; k < 8; ++k) w1_r[k] = physW1[k * 64 + lane];
    const float b1_r = physb1[lane];
    const float b2_r = physb2[lane];

    f32x4 cur8[2];
#pragma unroll
    for (int mt = 0; mt < 2; ++mt)
        cur8[mt] = *(const f32x4*)(latents + b * 32 + mt * 16 + q * 4);

    f32x4 tok[2][4];

    __syncthreads();  // biasL ready — the ONLY barrier

    auto stats = [&](f32x4 (&mean)[2], f32x4 (&rsig)[2]) {
#pragma unroll
        for (int mt = 0; mt < 2; ++mt)
#pragma unroll
            for (int r = 0; r < 4; ++r) {
                float s = (tok[mt][0][r] + tok[mt][1][r]) + (tok[mt][2][r] + tok[mt][3][r]);
                float qq = tok[mt][0][r] * tok[mt][0][r];
                qq = fmaf(tok[mt][1][r], tok[mt][1][r], qq);
                qq = fmaf(tok[mt][2][r], tok[mt][2][r], qq);
                qq = fmaf(tok[mt][3][r], tok[mt][3][r], qq);
                s = rowsum16(s); qq = rowsum16(qq);
                float m = s * 0.015625f;
                float v = fmaf(-m, m, qq * 0.015625f);
                mean[mt][r] = m;
                rsig[mt][r] = __builtin_amdgcn_rsqf(v + 1e-5f);
            }
    };

#pragma unroll 1
    for (int t = 0; t < Tt; ++t) {
        // ======== phys MLP (per wave, lane = w) ========
        {
            const float* pt = phys + ((size_t)b * Tt + t) * 8;
            float4 px0 = *(const float4*)pt, px1 = *(const float4*)(pt + 4);
            float a = b1_r;
            a = fmaf(px0.x, w1_r[0], a); a = fmaf(px0.y, w1_r[1], a);
            a = fmaf(px0.z, w1_r[2], a); a = fmaf(px0.w, w1_r[3], a);
            a = fmaf(px1.x, w1_r[4], a); a = fmaf(px1.y, w1_r[5], a);
            a = fmaf(px1.z, w1_r[6], a); a = fmaf(px1.w, w1_r[7], a);
            pvh[wv][lane] = gelu_f(a);
        }
        float pnt[4];
        {
            float acc = b2_r;
            const f32x4* w2p = (const f32x4*)(W2F + lane * 64);
            const f32x4* h4 = (const f32x4*)&pvh[wv][0];
#pragma unroll
            for (int kk = 0; kk < 16; ++kk) {
                f32x4 w4 = w2p[kk];
                f32x4 hv = h4[kk];
                acc = fmaf(hv[0], w4[0], acc); acc = fmaf(hv[1], w4[1], acc);
                acc = fmaf(hv[2], w4[2], acc); acc = fmaf(hv[3], w4[3], acc);
            }
            pvh[wv][64 + lane] = acc;
#pragma unroll
            for (int nt = 0; nt < 4; ++nt) pnt[nt] = pvh[wv][64 + nt * 16 + c];
        }

        // ======== token init (into C-layout regs) ========
#pragma unroll
        for (int nt = 0; nt < 4; ++nt) {
            const float basep = tokb_r[nt] + pnt[nt];
#pragma unroll
            for (int mt = 0; mt < 2; ++mt)
#pragma unroll
                for (int r = 0; r < 4; ++r)
                    tok[mt][nt][r] = fmaf(cur8[mt][r], tokw_r[nt], basep + pe_r[mt][nt][r]);
        }

#pragma unroll 1
        for (int il = 0; il < NL; ++il) {
            // ======== token mixing ========
            f32x4 mean[2], rsig[2];
            stats(mean, rsig);
            float tng[4], tnb[4];
#pragma unroll
            for (int nt = 0; nt < 4; ++nt) {
                tng[nt] = biasL[672 + il * 64 + nt * 16 + c];
                tnb[nt] = biasL[864 + il * 64 + nt * 16 + c];
            }
            // LN1 -> yB (B1 frags): row k = mt*16+q*4+r -> slot lane (mt*2+(q>>1))*16+c, j=(q&1)*4+r
#pragma unroll
            for (int mt = 0; mt < 2; ++mt)
#pragma unroll
                for (int nt = 0; nt < 4; ++nt) {
                    bf16x4 v4;
#pragma unroll
                    for (int r = 0; r < 4; ++r)
                        v4[r] = f2bf(fmaf((tok[mt][nt][r] - mean[mt][r]) * rsig[mt][r], tng[nt], tnb[nt]));
                    *(bf16x4*)&yb[(nt * 64 + (mt * 2 + (q >> 1)) * 16 + c) * 8 + (q & 1) * 4] = v4;
                }
            bf16x8 yfrag[4];
#pragma unroll
            for (int nt = 0; nt < 4; ++nt) yfrag[nt] = *(const bf16x8*)&yb[(nt * 64 + lane) * 8];

            // pre-add tob (per-row) into tok; mm2 then accumulates in place
#pragma unroll
            for (int mt = 0; mt < 2; ++mt) {
                const f32x4 tb = *(const f32x4*)&biasL[192 + il * 32 + mt * 16 + q * 4];
#pragma unroll
                for (int nt = 0; nt < 4; ++nt) tok[mt][nt] += tb;
            }
            // mm1 (gelu->hB half) + mm2 (into tok), split by K-half h
#pragma unroll
            for (int h = 0; h < 2; ++h) {
#pragma unroll
                for (int uu = 0; uu < 2; ++uu) {
                    const int u = h * 2 + uu;
                    const bf16x8 a1 = *(const bf16x8*)(tiWF + ((il * 4 + u) * 64 + lane) * 8);
                    const f32x4 bi = *(const f32x4*)&biasL[il * 64 + u * 16 + q * 4];
#pragma unroll
                    for (int nt = 0; nt < 4; ++nt) {
                        f32x4 acc = MFMA16(a1, yfrag[nt], bi);
                        bf16x4 g4;
#pragma unroll
                        for (int r = 0; r < 4; ++r) g4[r] = f2bf(gelu_f(acc[r]));
                        *(bf16x4*)&hb[(nt * 64 + (uu * 2 + (q >> 1)) * 16 + c) * 8 + (q & 1) * 4] = g4;
                    }
                }
                bf16x8 hf[4];
#pragma unroll
                for (int nt = 0; nt < 4; ++nt) hf[nt] = *(const bf16x8*)&hb[(nt * 64 + lane) * 8];
#pragma unroll
                for (int mt = 0; mt < 2; ++mt) {
                    const bf16x8 a2 = *(const bf16x8*)(toWF + ((il * 4 + mt * 2 + h) * 64 + lane) * 8);
#pragma unroll
                    for (int nt = 0; nt < 4; ++nt) tok[mt][nt] = MFMA16(a2, hf[nt], tok[mt][nt]);
                }
            }

            // ======== channel mixing ========
            stats(mean, rsig);
            float cng[4], cnb[4];
#pragma unroll
            for (int nt = 0; nt < 4; ++nt) {
                cng[nt] = biasL[1056 + il * 64 + nt * 16 + c];
                cnb[nt] = biasL[1248 + il * 64 + nt * 16 + c];
            }
            // LN2 -> y2B (B3 frags, swizzled slots; conflict-free b16 scatter)
#pragma unroll
            for (int mt = 0; mt < 2; ++mt)
#pragma unroll
                for (int nt = 0; nt < 4; ++nt)
#pragma unroll
                    for (int r = 0; r < 4; ++r) {
                        float v = fmaf((tok[mt][nt][r] - mean[mt][r]) * rsig[mt][r], cng[nt], cnb[nt]);
                        yb[(mt * 2 + (nt >> 1)) * 512 +
                           (q * 2 + (c >> 3) + 16 * r + 8 * (nt & 1)) * 8 + (c & 7)] = f2bf(v);
                    }
            bf16x8 b3[4];
            {
                const int lp = ((c >> 2) * 2 + (q & 1)) + 8 * ((c & 3) * 2 + (q >> 1));
#pragma unroll
                for (int F = 0; F < 4; ++F) b3[F] = *(const bf16x8*)&yb[F * 512 + lp * 8];
            }
            // pre-add cob (per-col) into tok; mm4 accumulates in place
#pragma unroll
            for (int nt = 0; nt < 4; ++nt) {
                const float cv = biasL[1440 + il * 64 + nt * 16 + c];
#pragma unroll
                for (int mt = 0; mt < 2; ++mt) tok[mt][nt] += cv;
            }

            // mm3 (gelu->h2A half) + mm4 (into tok), split by ch-half hh
            // ciW/coW fragments straight from L2 (prepacked in ws)
            const short* ciL = ciWF + il * 8192;
            const short* coL = coWF + il * 8192;
#pragma unroll
            for (int hh = 0; hh < 2; ++hh) {
#pragma unroll
                for (int mm = 0; mm < 4; ++mm) {
                    const int mtc = hh * 4 + mm;
                    const bf16x8 a30 = *(const bf16x8*)(ciL + ((mtc * 2 + 0) * 512 + lane * 8));
                    const bf16x8 a31 = *(const bf16x8*)(ciL + ((mtc * 2 + 1) * 512 + lane * 8));
                    const f32x4 bi3 = *(const f32x4*)&biasL[288 + il * 128 + mtc * 16 + q * 4];
#pragma unroll
                    for (int ntl = 0; ntl < 2; ++ntl) {
                        f32x4 acc = MFMA16(a30, b3[ntl * 2 + 0], bi3);
                        acc = MFMA16(a31, b3[ntl * 2 + 1], acc);
                        bf16x4 g4;
#pragma unroll
                        for (int r = 0; r < 4; ++r) g4[r] = f2bf(gelu_f(acc[r]));
                        *(bf16x4*)&hb[((ntl * 2 + ((mtc >> 1) & 1)) * 64 +
                                       ((mtc & 1) * 2 + (q >> 1)) * 16 + c) * 8 + (q & 1) * 4] = g4;
                    }
                }
                bf16x8 a4[2][2];
#pragma unroll
                for (int mt = 0; mt < 2; ++mt)
#pragma unroll
                    for (int kk = 0; kk < 2; ++kk)
                        a4[mt][kk] = *(const bf16x8*)&hb[((mt * 2 + kk) * 64 + lane) * 8];
#pragma unroll
                for (int nt = 0; nt < 4; ++nt) {
                    const bf16x8 b40 = *(const bf16x8*)(coL + ((nt * 4 + hh * 2 + 0) * 512 + lane * 8));
                    const bf16x8 b41 = *(const bf16x8*)(coL + ((nt * 4 + hh * 2 + 1) * 512 + lane * 8));
#pragma unroll
                    for (int mt = 0; mt < 2; ++mt) {
                        tok[mt][nt] = MFMA16(a4[mt][0], b40, tok[mt][nt]);
                        tok[mt][nt] = MFMA16(a4[mt][1], b41, tok[mt][nt]);
                    }
                }
            }
        }  // il

        // ======== head ========
        {
            f32x4 mean[2], rsig[2];
            stats(mean, rsig);
#pragma unroll
            for (int mt = 0; mt < 2; ++mt)
#pragma unroll
                for (int r = 0; r < 4; ++r) {
                    float l = (tok[mt][0][r] - mean[mt][r]) * gh_r[0];
                    l = fmaf(tok[mt][1][r] - mean[mt][r], gh_r[1], l);
                    l = fmaf(tok[mt][2][r] - mean[mt][r], gh_r[2], l);
                    l = fmaf(tok[mt][3][r] - mean[mt][r], gh_r[3], l);
                    l = rowsum16(l);
                    float nv = cur8[mt][r] + fmaf(rsig[mt][r], l, bh);
                    nv = fminf(fmaxf(nv, 0.f), 1.f);
                    cur8[mt][r] = nv;
                }
            if (c == 0) {
                float* op = out + ((size_t)b * Tt + t) * 32 + q * 4;
                *(f32x4*)(op) = cur8[0];
                *(f32x4*)(op + 16) = cur8[1];
            }
        }
    }  // t
}
}  // namespace

extern "C" void kernel_launch(void* const* d_in, const int* in_sizes, int n_in,
                              void* d_out, int out_size, void* d_ws, size_t ws_size,
                              hipStream_t stream) {
    (void)in_sizes; (void)n_in; (void)ws_size; (void)out_size;
    const float* phys    = (const float*)d_in[0];
    const float* latents = (const float*)d_in[1];
    const float* pos_emb = (const float*)d_in[2];
    const float* tokW    = (const float*)d_in[3];
    const float* tokb    = (const float*)d_in[4];
    const float* physW1  = (const float*)d_in[5];
    const float* physb1  = (const float*)d_in[6];
    const float* physW2  = (const float*)d_in[7];
    const float* physb2  = (const float*)d_in[8];
    const float* tn_g    = (const float*)d_in[9];
    const float* tn_b    = (const float*)d_in[10];
    const float* tiW     = (const float*)d_in[11];
    const float* tib     = (const float*)d_in[12];
    const float* toW     = (const float*)d_in[13];
    const float* tob     = (const float*)d_in[14];
    const float* cn_g    = (const float*)d_in[15];
    const float* cn_b    = (const float*)d_in[16];
    const float* ciW     = (const float*)d_in[17];
    const float* cib     = (const float*)d_in[18];
    const float* coW     = (const float*)d_in[19];
    const float* cob     = (const float*)d_in[20];
    const float* hn_g    = (const float*)d_in[21];
    const float* hn_b    = (const float*)d_in[22];
    const float* headW   = (const float*)d_in[23];
    const float* headb   = (const float*)d_in[24];

    lno_prep<<<dim3(256), dim3(256), 0, stream>>>(tiW, toW, ciW, coW, physW2, (short*)d_ws);
    lno_scan<<<dim3(512), dim3(256), 0, stream>>>(
        phys, latents, pos_emb, tokW, tokb, physW1, physb1, physb2,
        tn_g, tn_b, tib, tob, cn_g, cn_b, cib, cob, hn_g, hn_b, headW, headb,
        (const short*)d_ws, (float*)d_out);
}

// Round 5
// 7209.559 us; speedup vs baseline: 1.1491x; 1.1491x over previous
//
#include <hip/hip_runtime.h>
#include <math.h>

// Round 5: round-3 skeleton (one wave per batch, block-shared ciW/coW staging
// via global_load_lds, 2 barriers/layer) + fp16 datapath overhaul:
//  - all MFMA operands f16 (mfma_f32_16x16x32_f16, same fragment layout)
//  - packed transcendental-free GELU: x*(0.5 + t*P(t^2)), t=clamp(x,+-3),
//    degree-9 odd minimax in v_pk_fma_f16 (err ~3e-5 for |x|<=1; pre-acts
//    have sigma~0.1-0.16 so tails never hit)
//  - f32->f16 packing via single v_cvt_pkrtz_f16_f32 per pair
//  - physW2 fp32 in ws; LN params staged in LDS once
//
// Fragment layouts (gfx950, verified rounds 2-4):
//   A[m=lane&15][k=(lane>>4)*8+j], B[k=(lane>>4)*8+j][n=lane&15],
//   C: col=lane&15, row=(lane>>4)*4+reg.

namespace {
constexpr int Tt = 256, NL = 3;

typedef float    f32x4 __attribute__((ext_vector_type(4)));
typedef _Float16 half2 __attribute__((ext_vector_type(2)));
typedef _Float16 h16x8 __attribute__((ext_vector_type(8)));

#define MFMA16(a, b, c) __builtin_amdgcn_mfma_f32_16x16x32_f16((a), (b), (c), 0, 0, 0)

__device__ __forceinline__ half2 h2c(float v) { return (half2)((_Float16)v); }
__device__ __forceinline__ half2 pkrtz(float a, float b) {
    return __builtin_bit_cast(half2, __builtin_amdgcn_cvt_pkrtz(a, b));
}
__device__ __forceinline__ void st4h(short* p, half2 a, half2 b) {
    uint2 v;
    v.x = __builtin_bit_cast(unsigned int, a);
    v.y = __builtin_bit_cast(unsigned int, b);
    *(uint2*)p = v;
}
// packed f16 GELU, no transcendentals. s scaled by 1/8 to keep c4 normal in f16.
__device__ __forceinline__ half2 gelu_pk(half2 x) {
    half2 tc = __builtin_elementwise_min(__builtin_elementwise_max(x, h2c(-3.0f)), h2c(3.0f));
    half2 s = (tc * tc) * h2c(0.125f);
    half2 p = s * h2c(0.1455169f) + h2c(-0.446340f);
    p = s * p + h2c(0.604927f);
    p = s * p + h2c(-0.529702f);
    p = s * p + h2c(0.3989423f);
    return x * (h2c(0.5f) + tc * p);
}
// scalar f32 version (phys MLP only, 1/lane/step)
__device__ __forceinline__ float gelu_f(float x) {
    float tc = fminf(fmaxf(x, -3.f), 3.f);
    float s = tc * tc;
    float p = fmaf(s, 3.55266e-5f, -8.71758e-4f);
    p = fmaf(s, p, 9.45198e-3f);
    p = fmaf(s, p, -6.62128e-2f);
    p = fmaf(s, p, 0.3989423f);
    return x * fmaf(tc, p, 0.5f);
}
// sum across the 16-lane DPP row (all lanes get the total)
__device__ __forceinline__ float rowsum16(float x) {
    x += __builtin_bit_cast(float, __builtin_amdgcn_update_dpp(0, __builtin_bit_cast(int, x), 0x121, 0xf, 0xf, false));
    x += __builtin_bit_cast(float, __builtin_amdgcn_update_dpp(0, __builtin_bit_cast(int, x), 0x122, 0xf, 0xf, false));
    x += __builtin_bit_cast(float, __builtin_amdgcn_update_dpp(0, __builtin_bit_cast(int, x), 0x124, 0xf, 0xf, false));
    x += __builtin_bit_cast(float, __builtin_amdgcn_update_dpp(0, __builtin_bit_cast(int, x), 0x128, 0xf, 0xf, false));
    return x;
}

__device__ __forceinline__ short f2h(float x) {
    return __builtin_bit_cast(short, (_Float16)x);
}

// ws layout: shorts(f16) tiWF[0,6144) toWF[6144,12288) ciWF[12288,36864) coWF[36864,61440)
//            then fp32 W2F[4096] at short index 61440
__global__ void lno_prep(const float* __restrict__ tiW, const float* __restrict__ toW,
                         const float* __restrict__ ciW, const float* __restrict__ coW,
                         const float* __restrict__ physW2, short* __restrict__ wsf) {
    int id = blockIdx.x * 256 + threadIdx.x;  // 0..65535
    if (id < 6144) {            // A1: m=th, k=ld
        int j = id & 7, lane = (id >> 3) & 63, g = id >> 9;
        int il = g >> 2, u = g & 3;
        int m = u * 16 + (lane & 15), k = (lane >> 4) * 8 + j;
        wsf[id] = f2h(tiW[il * 2048 + k * 64 + m]);
    } else if (id < 12288) {    // A2: m=ld, k=th
        int t = id - 6144;
        int j = t & 7, lane = (t >> 3) & 63, g = t >> 9;
        int il = g >> 2, mt2 = (g >> 1) & 1, ks = g & 1;
        int m = mt2 * 16 + (lane & 15), k = ks * 32 + (lane >> 4) * 8 + j;
        wsf[id] = f2h(toW[il * 2048 + k * 32 + m]);
    } else if (id < 36864) {    // A3: m=ch, k=w
        int t = id - 12288;
        int j = t & 7, lane = (t >> 3) & 63, g = t >> 9;
        int il = g >> 4, mtc = (g >> 1) & 7, ks = g & 1;
        int m = mtc * 16 + (lane & 15), k = ks * 32 + (lane >> 4) * 8 + j;
        wsf[id] = f2h(ciW[il * 8192 + k * 128 + m]);
    } else if (id < 61440) {    // B4: k=ch, n=w
        int t = id - 36864;
        int j = t & 7, lane = (t >> 3) & 63, g = t >> 9;
        int il = g >> 4, nt = (g >> 2) & 3, ks = g & 3;
        int n = nt * 16 + (lane & 15), k = ks * 32 + (lane >> 4) * 8 + j;
        wsf[id] = f2h(coW[il * 8192 + k * 64 + n]);
    } else if (id < 65536) {    // W2F fp32 [w][k]
        int t = id - 61440;
        int w = t >> 6, k = t & 63;
        ((float*)(wsf + 61440))[t] = physW2[k * 64 + w];
    }
}

__global__ __launch_bounds__(256, 2) void lno_scan(
    const float* __restrict__ phys,   const float* __restrict__ latents,
    const float* __restrict__ pos_emb,const float* __restrict__ tokW,
    const float* __restrict__ tokb,   const float* __restrict__ physW1,
    const float* __restrict__ physb1, const float* __restrict__ physb2,
    const float* __restrict__ tn_g,   const float* __restrict__ tn_b,
    const float* __restrict__ tib,    const float* __restrict__ tob,
    const float* __restrict__ cn_g,   const float* __restrict__ cn_b,
    const float* __restrict__ cib,    const float* __restrict__ cob,
    const float* __restrict__ hn_g,   const float* __restrict__ hn_b,
    const float* __restrict__ headW,  const float* __restrict__ headb,
    const short* __restrict__ wsf,    float* __restrict__ out)
{
    __shared__ __align__(16) short bufA[4][2048];   // per-wave: yB (B1) then y2B (B3, swizzled)
    __shared__ __align__(16) short bufB[4][2048];   // per-wave: hB halves (B2) then h2A halves (A4)
    __shared__ __align__(16) short wbufC[8192];     // block-shared ciW frags (layer il)
    __shared__ __align__(16) short wbufO[8192];     // block-shared coW frags (layer il)
    __shared__ __align__(16) float biasL[1632];     // tib[0) tob[192) cib[288) tn_g[672) tn_b[864)
                                                    // cn_g[1056) cn_b[1248) cob[1440)
    __shared__ __align__(16) float pvh[4][128];     // per-wave phys h1 / p exchange

    const short* tiWF = wsf;
    const short* toWF = wsf + 6144;
    const short* ciWF = wsf + 12288;
    const short* coWF = wsf + 36864;
    const float* W2F  = (const float*)(wsf + 61440);

    const int tid = threadIdx.x, lane = tid & 63, wv = tid >> 6;
    const int q = lane >> 4, c = lane & 15;
    const int b = blockIdx.x * 4 + wv;

    short* yb = bufA[wv];
    short* hb = bufB[wv];

    // ---- stage biases + LN params into LDS (once) ----
    for (int i = tid; i < 192; i += 256) {
        biasL[i] = tib[i];
        biasL[672 + i]  = tn_g[i];
        biasL[864 + i]  = tn_b[i];
        biasL[1056 + i] = cn_g[i];
        biasL[1248 + i] = cn_b[i];
        biasL[1440 + i] = cob[i];
    }
    for (int i = tid; i < 96;  i += 256) biasL[192 + i] = tob[i];
    for (int i = tid; i < 384; i += 256) biasL[288 + i] = cib[i];

    // ---- hoisted per-lane constants ----
    float tokw_r[4], tokb_r[4], gh_r[4];
#pragma unroll
    for (int nt = 0; nt < 4; ++nt) {
        tokw_r[nt] = tokW[nt * 16 + c];
        tokb_r[nt] = tokb[nt * 16 + c];
        gh_r[nt]   = hn_g[nt * 16 + c] * headW[nt * 16 + c];
    }
    float bhp = 0.f;
#pragma unroll
    for (int nt = 0; nt < 4; ++nt) bhp = fmaf(hn_b[nt * 16 + c], headW[nt * 16 + c], bhp);
    const float bh = rowsum16(bhp) + headb[0];

    float pe_r[2][4][4];
#pragma unroll
    for (int mt = 0; mt < 2; ++mt)
#pragma unroll
        for (int nt = 0; nt < 4; ++nt)
#pragma unroll
            for (int r = 0; r < 4; ++r)
                pe_r[mt][nt][r] = pos_emb[(mt * 16 + q * 4 + r) * 64 + nt * 16 + c];

    float w1_r[8];
#pragma unroll
    for (int k = 0; k < 8; ++k) w1_r[k] = physW1[k * 64 + lane];
    const float b1_r = physb1[lane];
    const float b2_r = physb2[lane];

    f32x4 cur8[2];
#pragma unroll
    for (int mt = 0; mt < 2; ++mt)
        cur8[mt] = *(const f32x4*)(latents + b * 32 + mt * 16 + q * 4);

    f32x4 tok[2][4];

    __syncthreads();  // biasL ready

    auto stats = [&](f32x4 (&mean)[2], f32x4 (&rsig)[2]) {
#pragma unroll
        for (int mt = 0; mt < 2; ++mt)
#pragma unroll
            for (int r = 0; r < 4; ++r) {
                float s = (tok[mt][0][r] + tok[mt][1][r]) + (tok[mt][2][r] + tok[mt][3][r]);
                float qq = tok[mt][0][r] * tok[mt][0][r];
                qq = fmaf(tok[mt][1][r], tok[mt][1][r], qq);
                qq = fmaf(tok[mt][2][r], tok[mt][2][r], qq);
                qq = fmaf(tok[mt][3][r], tok[mt][3][r], qq);
                s = rowsum16(s); qq = rowsum16(qq);
                float m = s * 0.015625f;
                float v = fmaf(-m, m, qq * 0.015625f);
                mean[mt][r] = m;
                rsig[mt][r] = __builtin_amdgcn_rsqf(v + 1e-5f);
            }
    };

#pragma unroll 1
    for (int t = 0; t < Tt; ++t) {
        // ======== phys MLP (per wave, lane = w) ========
        {
            const float* pt = phys + ((size_t)b * Tt + t) * 8;
            float4 px0 = *(const float4*)pt, px1 = *(const float4*)(pt + 4);
            float a = b1_r;
            a = fmaf(px0.x, w1_r[0], a); a = fmaf(px0.y, w1_r[1], a);
            a = fmaf(px0.z, w1_r[2], a); a = fmaf(px0.w, w1_r[3], a);
            a = fmaf(px1.x, w1_r[4], a); a = fmaf(px1.y, w1_r[5], a);
            a = fmaf(px1.z, w1_r[6], a); a = fmaf(px1.w, w1_r[7], a);
            pvh[wv][lane] = gelu_f(a);
        }
        float pnt[4];
        {
            float acc = b2_r;
            const f32x4* w2p = (const f32x4*)(W2F + lane * 64);
            const f32x4* h4 = (const f32x4*)&pvh[wv][0];
#pragma unroll
            for (int kk = 0; kk < 16; ++kk) {
                f32x4 w4 = w2p[kk];
                f32x4 hv = h4[kk];
                acc = fmaf(hv[0], w4[0], acc); acc = fmaf(hv[1], w4[1], acc);
                acc = fmaf(hv[2], w4[2], acc); acc = fmaf(hv[3], w4[3], acc);
            }
            pvh[wv][64 + lane] = acc;
#pragma unroll
            for (int nt = 0; nt < 4; ++nt) pnt[nt] = pvh[wv][64 + nt * 16 + c];
        }

        // ======== token init (into C-layout regs) ========
#pragma unroll
        for (int nt = 0; nt < 4; ++nt) {
            const float basep = tokb_r[nt] + pnt[nt];
#pragma unroll
            for (int mt = 0; mt < 2; ++mt)
#pragma unroll
                for (int r = 0; r < 4; ++r)
                    tok[mt][nt][r] = fmaf(cur8[mt][r], tokw_r[nt], basep + pe_r[mt][nt][r]);
        }

#pragma unroll 1
        for (int il = 0; il < NL; ++il) {
            __syncthreads();  // (A) all waves done reading wbufC/wbufO
            {                 // stage ciW(il)->wbufC, coW(il)->wbufO (async DMA)
                const unsigned int* srcC = (const unsigned int*)(ciWF + il * 8192);
                const unsigned int* srcO = (const unsigned int*)(coWF + il * 8192);
#pragma unroll
                for (int i = 0; i < 4; ++i) {
                    const int chunk = i * 4 + wv;
                    __builtin_amdgcn_global_load_lds(srcC + chunk * 256 + lane * 4,
                                                     (unsigned int*)&wbufC[chunk * 512], 16, 0, 0);
                    __builtin_amdgcn_global_load_lds(srcO + chunk * 256 + lane * 4,
                                                     (unsigned int*)&wbufO[chunk * 512], 16, 0, 0);
                }
            }

            // ======== token mixing ========
            f32x4 mean[2], rsig[2];
            stats(mean, rsig);
            float tng[4], tnb[4];
#pragma unroll
            for (int nt = 0; nt < 4; ++nt) {
                tng[nt] = biasL[672 + il * 64 + nt * 16 + c];
                tnb[nt] = biasL[864 + il * 64 + nt * 16 + c];
            }
            // LN1 -> yB (B1 frags)
#pragma unroll
            for (int mt = 0; mt < 2; ++mt)
#pragma unroll
                for (int nt = 0; nt < 4; ++nt) {
                    float y0 = fmaf((tok[mt][nt][0] - mean[mt][0]) * rsig[mt][0], tng[nt], tnb[nt]);
                    float y1 = fmaf((tok[mt][nt][1] - mean[mt][1]) * rsig[mt][1], tng[nt], tnb[nt]);
                    float y2 = fmaf((tok[mt][nt][2] - mean[mt][2]) * rsig[mt][2], tng[nt], tnb[nt]);
                    float y3 = fmaf((tok[mt][nt][3] - mean[mt][3]) * rsig[mt][3], tng[nt], tnb[nt]);
                    st4h(&yb[(nt * 64 + (mt * 2 + (q >> 1)) * 16 + c) * 8 + (q & 1) * 4],
                         pkrtz(y0, y1), pkrtz(y2, y3));
                }
            h16x8 yfrag[4];
#pragma unroll
            for (int nt = 0; nt < 4; ++nt) yfrag[nt] = *(const h16x8*)&yb[(nt * 64 + lane) * 8];

            // pre-add tob (per-row) into tok; mm2 then accumulates in place
#pragma unroll
            for (int mt = 0; mt < 2; ++mt) {
                const f32x4 tb = *(const f32x4*)&biasL[192 + il * 32 + mt * 16 + q * 4];
#pragma unroll
                for (int nt = 0; nt < 4; ++nt) tok[mt][nt] += tb;
            }
            // mm1 (gelu->hB half) + mm2 (into tok), split by K-half h
#pragma unroll
            for (int h = 0; h < 2; ++h) {
#pragma unroll
                for (int uu = 0; uu < 2; ++uu) {
                    const int u = h * 2 + uu;
                    const h16x8 a1 = *(const h16x8*)(tiWF + ((il * 4 + u) * 64 + lane) * 8);
                    const f32x4 bi = *(const f32x4*)&biasL[il * 64 + u * 16 + q * 4];
#pragma unroll
                    for (int nt = 0; nt < 4; ++nt) {
                        f32x4 acc = MFMA16(a1, yfrag[nt], bi);
                        st4h(&hb[(nt * 64 + (uu * 2 + (q >> 1)) * 16 + c) * 8 + (q & 1) * 4],
                             gelu_pk(pkrtz(acc[0], acc[1])), gelu_pk(pkrtz(acc[2], acc[3])));
                    }
                }
                h16x8 hf[4];
#pragma unroll
                for (int nt = 0; nt < 4; ++nt) hf[nt] = *(const h16x8*)&hb[(nt * 64 + lane) * 8];
#pragma unroll
                for (int mt = 0; mt < 2; ++mt) {
                    const h16x8 a2 = *(const h16x8*)(toWF + ((il * 4 + mt * 2 + h) * 64 + lane) * 8);
#pragma unroll
                    for (int nt = 0; nt < 4; ++nt) tok[mt][nt] = MFMA16(a2, hf[nt], tok[mt][nt]);
                }
            }

            // ======== channel mixing ========
            stats(mean, rsig);
            float cng[4], cnb[4];
#pragma unroll
            for (int nt = 0; nt < 4; ++nt) {
                cng[nt] = biasL[1056 + il * 64 + nt * 16 + c];
                cnb[nt] = biasL[1248 + il * 64 + nt * 16 + c];
            }
            // LN2 -> y2B (B3 frags, swizzled slots; conflict-free b16 scatter)
#pragma unroll
            for (int mt = 0; mt < 2; ++mt)
#pragma unroll
                for (int nt = 0; nt < 4; ++nt)
#pragma unroll
                    for (int r = 0; r < 4; ++r) {
                        float v = fmaf((tok[mt][nt][r] - mean[mt][r]) * rsig[mt][r], cng[nt], cnb[nt]);
                        yb[(mt * 2 + (nt >> 1)) * 512 +
                           (q * 2 + (c >> 3) + 16 * r + 8 * (nt & 1)) * 8 + (c & 7)] = f2h(v);
                    }
            h16x8 b3[4];
            {
                const int lp = ((c >> 2) * 2 + (q & 1)) + 8 * ((c & 3) * 2 + (q >> 1));
#pragma unroll
                for (int F = 0; F < 4; ++F) b3[F] = *(const h16x8*)&yb[F * 512 + lp * 8];
            }
            // pre-add cob (per-col) into tok; mm4 accumulates in place
#pragma unroll
            for (int nt = 0; nt < 4; ++nt) {
                const float cv = biasL[1440 + il * 64 + nt * 16 + c];
#pragma unroll
                for (int mt = 0; mt < 2; ++mt) tok[mt][nt] += cv;
            }

            __syncthreads();  // (B) staged wbufC/wbufO ready (vmcnt drained)

            // mm3 (gelu->h2A half) + mm4 (into tok), split by ch-half hh
#pragma unroll
            for (int hh = 0; hh < 2; ++hh) {
#pragma unroll
                for (int mm = 0; mm < 4; ++mm) {
                    const int mtc = hh * 4 + mm;
                    const h16x8 a30 = *(const h16x8*)&wbufC[(mtc * 2 + 0) * 512 + lane * 8];
                    const h16x8 a31 = *(const h16x8*)&wbufC[(mtc * 2 + 1) * 512 + lane * 8];
                    const f32x4 bi3 = *(const f32x4*)&biasL[288 + il * 128 + mtc * 16 + q * 4];
#pragma unroll
                    for (int ntl = 0; ntl < 2; ++ntl) {
                        f32x4 acc = MFMA16(a30, b3[ntl * 2 + 0], bi3);
                        acc = MFMA16(a31, b3[ntl * 2 + 1], acc);
                        st4h(&hb[((ntl * 2 + ((mtc >> 1) & 1)) * 64 +
                                  ((mtc & 1) * 2 + (q >> 1)) * 16 + c) * 8 + (q & 1) * 4],
                             gelu_pk(pkrtz(acc[0], acc[1])), gelu_pk(pkrtz(acc[2], acc[3])));
                    }
                }
                h16x8 a4[2][2];
#pragma unroll
                for (int mt = 0; mt < 2; ++mt)
#pragma unroll
                    for (int kk = 0; kk < 2; ++kk)
                        a4[mt][kk] = *(const h16x8*)&hb[((mt * 2 + kk) * 64 + lane) * 8];
#pragma unroll
                for (int nt = 0; nt < 4; ++nt) {
                    const h16x8 b40 = *(const h16x8*)&wbufO[(nt * 4 + hh * 2 + 0) * 512 + lane * 8];
                    const h16x8 b41 = *(const h16x8*)&wbufO[(nt * 4 + hh * 2 + 1) * 512 + lane * 8];
#pragma unroll
                    for (int mt = 0; mt < 2; ++mt) {
                        tok[mt][nt] = MFMA16(a4[mt][0], b40, tok[mt][nt]);
                        tok[mt][nt] = MFMA16(a4[mt][1], b41, tok[mt][nt]);
                    }
                }
            }
        }  // il

        // ======== head ========
        {
            f32x4 mean[2], rsig[2];
            stats(mean, rsig);
#pragma unroll
            for (int mt = 0; mt < 2; ++mt)
#pragma unroll
                for (int r = 0; r < 4; ++r) {
                    float l = (tok[mt][0][r] - mean[mt][r]) * gh_r[0];
                    l = fmaf(tok[mt][1][r] - mean[mt][r], gh_r[1], l);
                    l = fmaf(tok[mt][2][r] - mean[mt][r], gh_r[2], l);
                    l = fmaf(tok[mt][3][r] - mean[mt][r], gh_r[3], l);
                    l = rowsum16(l);
                    float nv = cur8[mt][r] + fmaf(rsig[mt][r], l, bh);
                    nv = fminf(fmaxf(nv, 0.f), 1.f);
                    cur8[mt][r] = nv;
                }
            if (c == 0) {
                float* op = out + ((size_t)b * Tt + t) * 32 + q * 4;
                *(f32x4*)(op) = cur8[0];
                *(f32x4*)(op + 16) = cur8[1];
            }
        }
    }  // t
}
}  // namespace

extern "C" void kernel_launch(void* const* d_in, const int* in_sizes, int n_in,
                              void* d_out, int out_size, void* d_ws, size_t ws_size,
                              hipStream_t stream) {
    (void)in_sizes; (void)n_in; (void)ws_size; (void)out_size;
    const float* phys    = (const float*)d_in[0];
    const float* latents = (const float*)d_in[1];
    const float* pos_emb = (const float*)d_in[2];
    const float* tokW    = (const float*)d_in[3];
    const float* tokb    = (const float*)d_in[4];
    const float* physW1  = (const float*)d_in[5];
    const float* physb1  = (const float*)d_in[6];
    const float* physW2  = (const float*)d_in[7];
    const float* physb2  = (const float*)d_in[8];
    const float* tn_g    = (const float*)d_in[9];
    const float* tn_b    = (const float*)d_in[10];
    const float* tiW     = (const float*)d_in[11];
    const float* tib     = (const float*)d_in[12];
    const float* toW     = (const float*)d_in[13];
    const float* tob     = (const float*)d_in[14];
    const float* cn_g    = (const float*)d_in[15];
    const float* cn_b    = (const float*)d_in[16];
    const float* ciW     = (const float*)d_in[17];
    const float* cib     = (const float*)d_in[18];
    const float* coW     = (const float*)d_in[19];
    const float* cob     = (const float*)d_in[20];
    const float* hn_g    = (const float*)d_in[21];
    const float* hn_b    = (const float*)d_in[22];
    const float* headW   = (const float*)d_in[23];
    const float* headb   = (const float*)d_in[24];

    lno_prep<<<dim3(256), dim3(256), 0, stream>>>(tiW, toW, ciW, coW, physW2, (short*)d_ws);
    lno_scan<<<dim3(512), dim3(256), 0, stream>>>(
        phys, latents, pos_emb, tokW, tokb, physW1, physb1, physb2,
        tn_g, tn_b, tib, tob, cn_g, cn_b, cib, cob, hn_g, hn_b, headW, headb,
        (const short*)d_ws, (float*)d_out);
}